// Round 6
// baseline (224.372 us; speedup 1.0000x reference)
//
#include <hip/hip_runtime.h>

#define LSEQ 512
#define RCA 3.8f
#define ROWLEN 1539            // floats per output row
#define TILEF 1024             // floats per tile (4 KB; 64 lanes x 4 x f32x4)
#define NTILES 49248           // 50,429,952 / 1024

typedef float f32x4 __attribute__((ext_vector_type(4)));

// Affine 4x4 with implicit bottom row (0,0,0,1), stored as 3x4.
struct Aff { float m[3][4]; };

__device__ __forceinline__ Aff compose(const Aff& A, const Aff& B) {
    Aff C;
#pragma unroll
    for (int i = 0; i < 3; ++i) {
#pragma unroll
        for (int j = 0; j < 4; ++j) {
            float v = A.m[i][0] * B.m[0][j] + A.m[i][1] * B.m[1][j] + A.m[i][2] * B.m[2][j];
            if (j == 3) v += A.m[i][3];
            C.m[i][j] = v;
        }
    }
    return C;
}

__device__ __forceinline__ Aff shflUp(const Aff& a, int d) {
    Aff r;
#pragma unroll
    for (int i = 0; i < 3; ++i)
#pragma unroll
        for (int j = 0; j < 4; ++j)
            r.m[i][j] = __shfl_up(a.m[i][j], d, 64);
    return r;
}

__device__ __forceinline__ Aff makeB(float ca, float sa, float cb, float sb) {
    Aff B;
    B.m[0][0] = ca;  B.m[0][1] = -sa * cb; B.m[0][2] =  sa * sb; B.m[0][3] = RCA * ca;
    B.m[1][0] = sa;  B.m[1][1] =  ca * cb; B.m[1][2] = -ca * sb; B.m[1][3] = RCA * sa;
    B.m[2][0] = 0.f; B.m[2][1] =  sb;      B.m[2][2] =  cb;      B.m[2][3] = 0.f;
    return B;
}

// One block (512 threads = 8 waves) per batch. Thread tid owns l = tid.
__global__ __launch_bounds__(512) void scan_kernel(const float* __restrict__ angles,
                                                   float* __restrict__ F) {
    const int b = blockIdx.x;
    const int tid = threadIdx.x;   // = l
    const int lane = tid & 63;
    const int w = tid >> 6;

    __shared__ float sT[8][12];    // per-wave inclusive totals

    const float a  = angles[(size_t)b * 1024 + tid];
    const float be = angles[(size_t)b * 1024 + 512 + tid];
    float sa, ca, sb, cb;
    sincosf(a, &sa, &ca);
    sincosf(be, &sb, &cb);

    Aff S = makeB(ca, sa, cb, sb);
#pragma unroll
    for (int d = 1; d < 64; d <<= 1) {
        Aff o = shflUp(S, d);
        if (lane >= d) S = compose(o, S);
    }

    if (lane == 63) {
#pragma unroll
        for (int k = 0; k < 12; ++k) sT[w][k] = S.m[k / 4][k % 4];
    }
    __syncthreads();

    Aff E;
#pragma unroll
    for (int i = 0; i < 3; ++i)
#pragma unroll
        for (int j = 0; j < 4; ++j) E.m[i][j] = (i == j) ? 1.f : 0.f;
    for (int k = 0; k < w; ++k) {
        Aff T;
#pragma unroll
        for (int q = 0; q < 12; ++q) T.m[q / 4][q % 4] = sT[k][q];
        E = compose(E, T);
    }

    const Aff Sp = shflUp(S, 1);
    const Aff M = compose(E, S);                      // inclusive prefix at l
    Aff Mprev;
    if (lane == 0) Mprev = E;
    else           Mprev = compose(E, Sp);            // inclusive prefix at l-1

    float Rt[3][3], ti[3];
#pragma unroll
    for (int i = 0; i < 3; ++i)
#pragma unroll
        for (int j = 0; j < 3; ++j) Rt[i][j] = M.m[j][i];
#pragma unroll
    for (int i = 0; i < 3; ++i)
        ti[i] = -(M.m[0][i] * M.m[0][3] + M.m[1][i] * M.m[1][3] + M.m[2][i] * M.m[2][3]);

    float d0[4] = {-sa, -ca * cb,  ca * sb, -RCA * sa};
    float d1[4] = { ca, -sa * cb,  sa * sb,  RCA * ca};
    float e01 =  sa * sb, e02 =  sa * cb;
    float e11 = -ca * sb, e12 = -ca * cb;
    float e21 =  cb,      e22 = -sb;

    float Ga[3][4], Gb[3][4];
#pragma unroll
    for (int i = 0; i < 3; ++i) {
        float p0 = Mprev.m[i][0], p1 = Mprev.m[i][1], p2 = Mprev.m[i][2];
#pragma unroll
        for (int j = 0; j < 4; ++j) Ga[i][j] = p0 * d0[j] + p1 * d1[j];
        Gb[i][0] = 0.f;
        Gb[i][1] = p0 * e01 + p1 * e11 + p2 * e21;
        Gb[i][2] = p0 * e02 + p1 * e12 + p2 * e22;
        Gb[i][3] = 0.f;
    }

    float W[24];
#pragma unroll
    for (int i = 0; i < 3; ++i) {
#pragma unroll
        for (int j = 0; j < 3; ++j) {
            W[i * 4 + j]      = Ga[i][0] * Rt[0][j] + Ga[i][1] * Rt[1][j] + Ga[i][2] * Rt[2][j];
            W[12 + i * 4 + j] = Gb[i][0] * Rt[0][j] + Gb[i][1] * Rt[1][j] + Gb[i][2] * Rt[2][j];
        }
        W[i * 4 + 3]      = Ga[i][0] * ti[0] + Ga[i][1] * ti[1] + Ga[i][2] * ti[2] + Ga[i][3];
        W[12 + i * 4 + 3] = Gb[i][0] * ti[0] + Gb[i][1] * ti[1] + Gb[i][2] * ti[2] + Gb[i][3];
    }

    f32x4* w4 = reinterpret_cast<f32x4*>(F + ((size_t)b * LSEQ + tid) * 24);
    const f32x4* s4 = reinterpret_cast<const f32x4*>(W);
#pragma unroll
    for (int q = 0; q < 6; ++q) w4[q] = s4[q];
}

// Wave-tiled streamer, 4 KB tiles (64 lanes x 4 x f32x4), grid-strided.
// ALL output stores are nontemporal (output is write-once, never re-read):
// if the ~2.5 TB/s cap seen by every previous structure is the L2
// write-allocate/eviction path, nt should lift it.
// A wave-uniform test skips fully-masked tiles (~84%): one nt-store x4 per
// lane, no loads. Active tiles take a per-element path with all row
// descriptors hoisted (tile touches at most 2 rows since TILEF < ROWLEN).
__global__ __launch_bounds__(256) void emit_kernel(const float* __restrict__ F,
                                                   const float* __restrict__ coords,
                                                   const int* __restrict__ lens,
                                                   float* __restrict__ out) {
    const int lane = threadIdx.x & 63;
    int wid0 = blockIdx.x * 4 + (threadIdx.x >> 6);
    wid0 = __builtin_amdgcn_readfirstlane(wid0);      // keep tile index scalar
    const int nW = gridDim.x * 4;

    for (int t = wid0; t < NTILES; t += nW) {
        const long long Tel = (long long)t * TILEF;   // tile's first element
        // row = Tel / 1539 via magic multiply (exact for n < 2.2e9)
        const int r0   = (int)(((unsigned long long)Tel * 1428865014ull) >> 41);
        const int relT = (int)(Tel - (long long)r0 * ROWLEN);
        const bool spill = (relT + TILEF > ROWLEN);   // tile touches row r0+1

        // ---- hoisted row descriptors (wave-uniform) ----
        const int l0 = r0 & 511, b0 = r0 >> 10, p0 = (r0 >> 9) & 1;
        int len0 = lens[b0]; if (len0 > 511) len0 = 511;
        int l1 = 0, b1 = 0, p1 = 0, len1 = 0;
        if (spill) {                                  // r0+1 <= 32767 always here
            const int r1 = r0 + 1;
            l1 = r1 & 511; b1 = r1 >> 10; p1 = (r1 >> 9) & 1;
            len1 = lens[b1]; if (len1 > 511) len1 = 511;
        }

        // ---- wave-uniform active test ----
        bool act = false;
        if (l0 < len0) {
            const int lo = 3 * (l0 + 1), hi = 3 * len0 + 3;     // active [lo, hi)
            const int e0 = spill ? ROWLEN : relT + TILEF;
            act = (relT < hi) && (e0 > lo);
        }
        if (!act && spill && (l1 < len1)) {
            act = ((relT + TILEF - ROWLEN) > 3 * (l1 + 1));     // row1 part [0, e1)
        }

        float* const tp = out + Tel + lane * 4;
        if (!act) {                                   // uniform branch -> s_cbranch
            const f32x4 z = {0.f, 0.f, 0.f, 0.f};
#pragma unroll
            for (int k = 0; k < 4; ++k)
                __builtin_nontemporal_store(z, reinterpret_cast<f32x4*>(tp + k * 256));
        } else {
            const float* const fB0 = F + ((size_t)(b0 * 512 + l0)) * 24 + p0 * 12;
            const float* const fB1 = F + ((size_t)(b1 * 512 + l1)) * 24 + p1 * 12;
            const float* const cB0 = coords + (size_t)b0 * ROWLEN;
            const float* const cB1 = coords + (size_t)b1 * ROWLEN;
#pragma unroll
            for (int k = 0; k < 4; ++k) {
                const int relLane = relT + k * 256 + lane * 4;
                f32x4 v = {0.f, 0.f, 0.f, 0.f};
#pragma unroll
                for (int j = 0; j < 4; ++j) {
                    int rel = relLane + j;
                    const bool c1 = (rel >= ROWLEN);
                    if (c1) rel -= ROWLEN;
                    const int l   = c1 ? l1 : l0;
                    const int len = c1 ? len1 : len0;
                    if (l < len && rel >= 3 * (l + 1) && rel < 3 * len + 3) {
                        const int m = (rel * 43691) >> 17;      // rel/3, exact
                        const int c = rel - 3 * m;
                        const float* fa = (c1 ? fB1 : fB0) + c * 4;
                        const float* cp = (c1 ? cB1 : cB0) + 3 * m;
                        v[j] = fa[0] * cp[0] + fa[1] * cp[1] + fa[2] * cp[2] + fa[3];
                    }
                }
                __builtin_nontemporal_store(v, reinterpret_cast<f32x4*>(tp + k * 256));
            }
        }
    }
}

extern "C" void kernel_launch(void* const* d_in, const int* in_sizes, int n_in,
                              void* d_out, int out_size, void* d_ws, size_t ws_size,
                              hipStream_t stream) {
    const float* angles = (const float*)d_in[0];   // fp32 (32, 2, 512)
    const float* coords = (const float*)d_in[1];   // fp32 (32, 1539)
    const int*   lens   = (const int*)d_in[2];     // int32 (32,)
    float* out = (float*)d_out;                    // fp32 output
    float* F = (float*)d_ws;                       // 32*512*24 fp32 = 1.57 MB scratch

    scan_kernel<<<32, 512, 0, stream>>>(angles, F);
    // 2048 blocks x 4 waves = 8192 waves; 49248 tiles -> ~6 tiles/wave
    emit_kernel<<<2048, 256, 0, stream>>>(F, coords, lens, out);
}

// Round 7
// 205.679 us; speedup vs baseline: 1.0909x; 1.0909x over previous
//
#include <hip/hip_runtime.h>

#define LSEQ 512
#define RCA 3.8f

// Affine 4x4 with implicit bottom row (0,0,0,1), stored as 3x4.
struct Aff { float m[3][4]; };

__device__ __forceinline__ Aff compose(const Aff& A, const Aff& B) {
    Aff C;
#pragma unroll
    for (int i = 0; i < 3; ++i) {
#pragma unroll
        for (int j = 0; j < 4; ++j) {
            float v = A.m[i][0] * B.m[0][j] + A.m[i][1] * B.m[1][j] + A.m[i][2] * B.m[2][j];
            if (j == 3) v += A.m[i][3];
            C.m[i][j] = v;
        }
    }
    return C;
}

__device__ __forceinline__ Aff shflUp(const Aff& a, int d) {
    Aff r;
#pragma unroll
    for (int i = 0; i < 3; ++i)
#pragma unroll
        for (int j = 0; j < 4; ++j)
            r.m[i][j] = __shfl_up(a.m[i][j], d, 64);
    return r;
}

__device__ __forceinline__ Aff makeB(float ca, float sa, float cb, float sb) {
    Aff B;
    B.m[0][0] = ca;  B.m[0][1] = -sa * cb; B.m[0][2] =  sa * sb; B.m[0][3] = RCA * ca;
    B.m[1][0] = sa;  B.m[1][1] =  ca * cb; B.m[1][2] = -ca * sb; B.m[1][3] = RCA * sa;
    B.m[2][0] = 0.f; B.m[2][1] =  sb;      B.m[2][2] =  cb;      B.m[2][3] = 0.f;
    return B;
}

// One block (512 threads = 8 waves) per batch. Thread tid owns l = tid.
// Wave-level scan + cross-wave combine. F[(b*512+l)*24 + {0..23}] = {Fa, Fb}.
__global__ __launch_bounds__(512) void scan_kernel(const float* __restrict__ angles,
                                                   float* __restrict__ F) {
    const int b = blockIdx.x;
    const int tid = threadIdx.x;   // = l
    const int lane = tid & 63;
    const int w = tid >> 6;

    __shared__ float sT[8][12];    // per-wave inclusive totals

    const float a  = angles[(size_t)b * 1024 + tid];
    const float be = angles[(size_t)b * 1024 + 512 + tid];
    float sa, ca, sb, cb;
    sincosf(a, &sa, &ca);
    sincosf(be, &sb, &cb);

    // wave-inclusive scan of single matrices
    Aff S = makeB(ca, sa, cb, sb);
#pragma unroll
    for (int d = 1; d < 64; d <<= 1) {
        Aff o = shflUp(S, d);
        if (lane >= d) S = compose(o, S);
    }

    if (lane == 63) {
#pragma unroll
        for (int k = 0; k < 12; ++k) sT[w][k] = S.m[k / 4][k % 4];
    }
    __syncthreads();

    // exclusive cross-wave prefix E_w = T_0 @ ... @ T_{w-1}
    Aff E;
#pragma unroll
    for (int i = 0; i < 3; ++i)
#pragma unroll
        for (int j = 0; j < 4; ++j) E.m[i][j] = (i == j) ? 1.f : 0.f;
    for (int k = 0; k < w; ++k) {
        Aff T;
#pragma unroll
        for (int q = 0; q < 12; ++q) T.m[q / 4][q % 4] = sT[k][q];
        E = compose(E, T);
    }

    const Aff Sp = shflUp(S, 1);
    const Aff M = compose(E, S);                      // inclusive prefix at l
    Aff Mprev;
    if (lane == 0) Mprev = E;
    else           Mprev = compose(E, Sp);            // inclusive prefix at l-1

    // ---- epilogue: Fa/Fb = Mprev @ dB @ Minv ----
    float Rt[3][3], ti[3];
#pragma unroll
    for (int i = 0; i < 3; ++i)
#pragma unroll
        for (int j = 0; j < 3; ++j) Rt[i][j] = M.m[j][i];
#pragma unroll
    for (int i = 0; i < 3; ++i)
        ti[i] = -(M.m[0][i] * M.m[0][3] + M.m[1][i] * M.m[1][3] + M.m[2][i] * M.m[2][3]);

    // dB_da: rows 0,1 nonzero
    float d0[4] = {-sa, -ca * cb,  ca * sb, -RCA * sa};
    float d1[4] = { ca, -sa * cb,  sa * sb,  RCA * ca};
    // dB_db: cols 1,2 nonzero
    float e01 =  sa * sb, e02 =  sa * cb;
    float e11 = -ca * sb, e12 = -ca * cb;
    float e21 =  cb,      e22 = -sb;

    float Ga[3][4], Gb[3][4];
#pragma unroll
    for (int i = 0; i < 3; ++i) {
        float p0 = Mprev.m[i][0], p1 = Mprev.m[i][1], p2 = Mprev.m[i][2];
#pragma unroll
        for (int j = 0; j < 4; ++j) Ga[i][j] = p0 * d0[j] + p1 * d1[j];
        Gb[i][0] = 0.f;
        Gb[i][1] = p0 * e01 + p1 * e11 + p2 * e21;
        Gb[i][2] = p0 * e02 + p1 * e12 + p2 * e22;
        Gb[i][3] = 0.f;
    }

    float W[24];
#pragma unroll
    for (int i = 0; i < 3; ++i) {
#pragma unroll
        for (int j = 0; j < 3; ++j) {
            W[i * 4 + j]      = Ga[i][0] * Rt[0][j] + Ga[i][1] * Rt[1][j] + Ga[i][2] * Rt[2][j];
            W[12 + i * 4 + j] = Gb[i][0] * Rt[0][j] + Gb[i][1] * Rt[1][j] + Gb[i][2] * Rt[2][j];
        }
        W[i * 4 + 3]      = Ga[i][0] * ti[0] + Ga[i][1] * ti[1] + Ga[i][2] * ti[2] + Ga[i][3];
        W[12 + i * 4 + 3] = Gb[i][0] * ti[0] + Gb[i][1] * ti[1] + Gb[i][2] * ti[2] + Gb[i][3];
    }

    float4* w4 = reinterpret_cast<float4*>(F + ((size_t)b * LSEQ + tid) * 24);
    const float4* s4 = reinterpret_cast<const float4*>(W);
#pragma unroll
    for (int q = 0; q < 6; ++q) w4[q] = s4[q];
}

// grid (128, 32), block 256. Block handles l = 4*bx .. 4*bx+3 for batch by.
__global__ __launch_bounds__(256) void emit_kernel(const float* __restrict__ F,
                                                   const float* __restrict__ coords,
                                                   const int* __restrict__ lens,
                                                   float* __restrict__ out) {
    const int b = blockIdx.y;
    const int l0 = blockIdx.x * 4;
    const int tid = threadIdx.x;

    __shared__ float sF[96];
    if (tid < 96) sF[tid] = F[((size_t)b * LSEQ + l0) * 24 + tid];
    __syncthreads();

    const int len = lens[b];
    const float* cp = coords + (size_t)b * 1539;

    // preload coords for m = tid, tid+256, (tid+512 when valid: tid==0)
    const int m0 = tid, m1 = tid + 256, m2 = tid + 512;
    const float cx0 = cp[m0 * 3], cy0 = cp[m0 * 3 + 1], cz0 = cp[m0 * 3 + 2];
    const float cx1 = cp[m1 * 3], cy1 = cp[m1 * 3 + 1], cz1 = cp[m1 * 3 + 2];
    const bool has2 = (m2 < 513);
    float cx2 = 0.f, cy2 = 0.f, cz2 = 0.f;
    if (has2) { cx2 = cp[m2 * 3]; cy2 = cp[m2 * 3 + 1]; cz2 = cp[m2 * 3 + 2]; }

#pragma unroll
    for (int i = 0; i < 4; ++i) {
        const int l = l0 + i;
        const float* f = sF + i * 24;
        const float f00 = f[0],  f01 = f[1],  f02 = f[2],  f03 = f[3];
        const float f10 = f[4],  f11 = f[5],  f12 = f[6],  f13 = f[7];
        const float f20 = f[8],  f21 = f[9],  f22 = f[10], f23 = f[11];
        const float g00 = f[12], g01 = f[13], g02 = f[14], g03 = f[15];
        const float g10 = f[16], g11 = f[17], g12 = f[18], g13 = f[19];
        const float g20 = f[20], g21 = f[21], g22 = f[22], g23 = f[23];

        const size_t baseA = ((size_t)(b * 2) * LSEQ + l) * 1539;
        const size_t baseB = baseA + (size_t)LSEQ * 1539;
        const bool rowActive = (l < len);

        auto emit1 = [&](int m, float x, float y, float z) {
            const float s = (rowActive && (m > l) && (m <= len)) ? 1.f : 0.f;
            float3 va, vb;
            va.x = s * (f00 * x + f01 * y + f02 * z + f03);
            va.y = s * (f10 * x + f11 * y + f12 * z + f13);
            va.z = s * (f20 * x + f21 * y + f22 * z + f23);
            vb.x = s * (g00 * x + g01 * y + g02 * z + g03);
            vb.y = s * (g10 * x + g11 * y + g12 * z + g13);
            vb.z = s * (g20 * x + g21 * y + g22 * z + g23);
            *reinterpret_cast<float3*>(out + baseA + (size_t)m * 3) = va;
            *reinterpret_cast<float3*>(out + baseB + (size_t)m * 3) = vb;
        };

        emit1(m0, cx0, cy0, cz0);
        emit1(m1, cx1, cy1, cz1);
        if (has2) emit1(m2, cx2, cy2, cz2);
    }
}

extern "C" void kernel_launch(void* const* d_in, const int* in_sizes, int n_in,
                              void* d_out, int out_size, void* d_ws, size_t ws_size,
                              hipStream_t stream) {
    const float* angles = (const float*)d_in[0];   // fp32 (32, 2, 512)
    const float* coords = (const float*)d_in[1];   // fp32 (32, 1539)
    const int*   lens   = (const int*)d_in[2];     // int32 (32,)
    float* out = (float*)d_out;                    // fp32 output
    float* F = (float*)d_ws;                       // 32*512*24 fp32 = 1.57 MB scratch

    scan_kernel<<<32, 512, 0, stream>>>(angles, F);
    emit_kernel<<<dim3(128, 32), 256, 0, stream>>>(F, coords, lens, out);
}